// Round 2
// baseline (510.264 us; speedup 1.0000x reference)
//
#include <hip/hip_runtime.h>
#include <hip/hip_bf16.h>
#include <float.h>

// Problem constants
#define NB 128
#define DD 64
#define HH 32
#define WW 32
#define NTOT (NB*HH*WW)     // 131072
#define KC 512
#define HWSZ 1024

// d_out element offsets (fp32, concatenated in return order)
#define OFF_LOSS  0
#define OFF_QUANT 1
#define OFF_PERP  8388609
#define OFF_OH    8388610

// ws word layout: [0] loss accum (float); [1..512] counts (int);
// [1024..1535] enorm (float); [2048..] idx (int, NTOT)
#define WS_COUNTS 1
#define WS_ENORM  1024
#define WS_IDX    2048

__global__ __launch_bounds__(256)
void vq_prep(const float* __restrict__ cb, float* __restrict__ ws) {
    int t = blockIdx.x * 256 + threadIdx.x;   // 0..511
    if (t == 0) ws[0] = 0.0f;
    ((int*)ws)[WS_COUNTS + t] = 0;
    const float4* row = (const float4*)(cb + (t << 6));
    float s = 0.0f;
#pragma unroll
    for (int i = 0; i < 16; ++i) {
        float4 v = row[i];
        s = fmaf(v.x, v.x, s); s = fmaf(v.y, v.y, s);
        s = fmaf(v.z, v.z, s); s = fmaf(v.w, v.w, s);
    }
    ws[WS_ENORM + t] = s;
}

// Main fused distance + argmin kernel.
// Grid: NTOT/64 = 2048 WGs of 256 threads.
// WG tile: 64 rows (x vectors), K processed in 4 tiles of 128 codes.
// Thread tile: 4 rows x 8 cols (cols strided by 16 for conflict-free LDS reads).
#define TILE_K 128
#define EU_LD  65   // pad: bank = (tc + 16j + d) % 32 -> conflict-free

__global__ __launch_bounds__(256)
void vq_argmin(const float* __restrict__ x, const float* __restrict__ cb,
               const float* __restrict__ ws, int* __restrict__ idx_out,
               int* __restrict__ counts, float* __restrict__ loss_acc) {
    // LDS carve: Xs[64][64] | Eu[128][65] (aliased by reduction arrays) | xn[64] | wls[64]
    __shared__ float smem[4096 + TILE_K*EU_LD + 64 + 64];
    float (*Xs)[64]    = (float(*)[64])smem;
    float (*Eu)[EU_LD] = (float(*)[EU_LD])(smem + 4096);
    float* xn  = smem + 4096 + TILE_K*EU_LD;
    float* wls = xn + 64;
    // reduction arrays alias the Eu region (used only after last Eu read)
    float* redv1 = smem + 4096;            // [16][64]
    int*   redi1 = (int*)(redv1 + 1024);
    float* redv2 = redv1 + 2048;
    int*   redi2 = (int*)(redv1 + 3072);

    const float* enorm = ws + WS_ENORM;
    int t  = threadIdx.x;
    int wg = blockIdx.x;
    int n0 = wg * 64;
    int b  = n0 >> 10;
    int sp0 = n0 & 1023;
    const float* xbase = x + ((size_t)b << 16) + sp0;   // + d*1024 + row

    // ---- stage X tile: Xs[d][row], coalesced float4 global loads ----
#pragma unroll
    for (int i = 0; i < 4; ++i) {
        int e4 = i * 256 + t;          // 0..1023 float4 units
        int d  = e4 >> 4;
        int r4 = (e4 & 15) << 2;
        float4 v = *(const float4*)(xbase + (size_t)d * 1024 + r4);
        *(float4*)&Xs[d][r4] = v;
    }
    __syncthreads();

    // xnorm per row (one-time)
    if (t < 64) {
        float s = 0.0f;
        for (int d = 0; d < 64; ++d) { float v = Xs[d][t]; s = fmaf(v, v, s); }
        xn[t] = s;
    }

    int tr = t >> 4, tc = t & 15;
    int rb = tr << 2;

    float v1[4], v2[4];
    int   i1[4], i2[4];
#pragma unroll
    for (int i = 0; i < 4; ++i) { v1[i] = FLT_MAX; v2[i] = FLT_MAX; i1[i] = 0; i2[i] = 0; }

    for (int kt = 0; kt < 4; ++kt) {
        int k0 = kt * TILE_K;
        __syncthreads();   // previous compute done before overwriting Eu
        // ---- stage E tile: Eu[k][d], coalesced float4 global, 2-way LDS writes ----
#pragma unroll
        for (int i = 0; i < 8; ++i) {
            int f  = i * 256 + t;       // 0..2047 float4 units
            int k  = f >> 4;            // 0..127
            int d4 = (f & 15) << 2;
            float4 v = *(const float4*)(cb + (size_t)(k0 + k) * 64 + d4);
            Eu[k][d4+0] = v.x; Eu[k][d4+1] = v.y; Eu[k][d4+2] = v.z; Eu[k][d4+3] = v.w;
        }
        __syncthreads();

        float acc[4][8];
#pragma unroll
        for (int i = 0; i < 4; ++i)
#pragma unroll
            for (int j = 0; j < 8; ++j) acc[i][j] = 0.0f;

#pragma unroll 8
        for (int d = 0; d < 64; ++d) {
            float4 xa = *(const float4*)&Xs[d][rb];
            float ev[8];
#pragma unroll
            for (int j = 0; j < 8; ++j) ev[j] = Eu[tc + 16*j][d];
#pragma unroll
            for (int j = 0; j < 8; ++j) {
                acc[0][j] = fmaf(xa.x, ev[j], acc[0][j]);
                acc[1][j] = fmaf(xa.y, ev[j], acc[1][j]);
                acc[2][j] = fmaf(xa.z, ev[j], acc[2][j]);
                acc[3][j] = fmaf(xa.w, ev[j], acc[3][j]);
            }
        }

        // update per-row top-2 (k ascending within thread -> strict < keeps first)
#pragma unroll
        for (int j = 0; j < 8; ++j) {
            int k = k0 + tc + 16*j;
            float en = enorm[k];
#pragma unroll
            for (int i = 0; i < 4; ++i) {
                float s = fmaf(-2.0f, acc[i][j], en);   // ||e||^2 - 2 x.e
                if (s < v1[i]) { v2[i] = v1[i]; i2[i] = i1[i]; v1[i] = s; i1[i] = k; }
                else if (s < v2[i]) { v2[i] = s; i2[i] = k; }
            }
        }
    }

    __syncthreads();   // all compute done; safe to alias Eu region
#pragma unroll
    for (int i = 0; i < 4; ++i) {
        redv1[tc*64 + rb + i] = v1[i];
        redi1[tc*64 + rb + i] = i1[i];
        redv2[tc*64 + rb + i] = v2[i];
        redi2[tc*64 + rb + i] = i2[i];
    }
    __syncthreads();

    if (t < 64) {
        float V1 = FLT_MAX, V2 = FLT_MAX;
        int   I1 = 0x7fffffff, I2 = 0x7fffffff;
        for (int c = 0; c < 16; ++c) {
            float a1 = redv1[c*64 + t]; int j1 = redi1[c*64 + t];
            float a2 = redv2[c*64 + t]; int j2 = redi2[c*64 + t];
            if (a1 < V1 || (a1 == V1 && j1 < I1)) {
                V2 = V1; I2 = I1; V1 = a1; I1 = j1;
            } else if (a1 < V2) { V2 = a1; I2 = j1; }
            if (a2 < V2) { V2 = a2; I2 = j2; }
        }
        float mind;
        if (V2 - V1 < 5e-3f) {
            // near-tie: decide exactly in fp64 (matches true/np argmin)
            const float* c1 = cb + ((size_t)I1 << 6);
            const float* c2 = cb + ((size_t)I2 << 6);
            double d1 = 0.0, d2 = 0.0;
            for (int d = 0; d < 64; ++d) {
                double xv = (double)Xs[d][t];
                double t1 = xv - (double)c1[d];
                double t2 = xv - (double)c2[d];
                d1 += t1*t1; d2 += t2*t2;
            }
            if (d2 < d1 || (d2 == d1 && I2 < I1)) { I1 = I2; mind = (float)d2; }
            else mind = (float)d1;
        } else {
            mind = xn[t] + V1;
        }
        idx_out[n0 + t] = I1;
        atomicAdd(&counts[I1], 1);
        wls[t] = mind;
    }
    __syncthreads();
    if (t == 0) {
        float s = 0.0f;
        for (int r = 0; r < 64; ++r) s += wls[r];
        atomicAdd(loss_acc, s);
    }
}

// quantized_out[b][d][h][w] = codebook[idx[n]][d], coalesced stores over sp
__global__ __launch_bounds__(256)
void vq_quant(const float* __restrict__ cb, const int* __restrict__ idx,
              float* __restrict__ qout) {
    int n = blockIdx.x * 256 + threadIdx.x;    // grid 512 -> 131072
    int b = n >> 10, sp = n & 1023;
    int k = idx[n];
    const float4* row = (const float4*)(cb + ((size_t)k << 6));
    float* obase = qout + (((size_t)b << 6) << 10) + sp;
#pragma unroll
    for (int d4 = 0; d4 < 16; ++d4) {
        float4 v = row[d4];
        obase[(size_t)(4*d4 + 0) * 1024] = v.x;
        obase[(size_t)(4*d4 + 1) * 1024] = v.y;
        obase[(size_t)(4*d4 + 2) * 1024] = v.z;
        obase[(size_t)(4*d4 + 3) * 1024] = v.w;
    }
}

// oh[b][k][sp] = (idx[b*1024+sp] == k), single pass (writes the zeros too).
// oh base is only 8B-aligned (element offset 8388610) -> float2 stores.
__global__ __launch_bounds__(256)
void vq_onehot(const int* __restrict__ idx, float* __restrict__ oh) {
    int tid = blockIdx.x * 256 + threadIdx.x;  // 0..16777215, 4 elems each
    int e0 = tid << 2;
    int sp = e0 & 1023;
    int bk = e0 >> 10;
    int k  = bk & 511;
    int b  = bk >> 9;
    int4 iv = *(const int4*)(idx + (b << 10) + sp);
    float2 lo = { iv.x == k ? 1.0f : 0.0f, iv.y == k ? 1.0f : 0.0f };
    float2 hi = { iv.z == k ? 1.0f : 0.0f, iv.w == k ? 1.0f : 0.0f };
    float* p = oh + e0;
    *(float2*)p = lo;
    *(float2*)(p + 2) = hi;
}

__global__ __launch_bounds__(512)
void vq_final(const float* __restrict__ ws, float* __restrict__ out) {
    __shared__ float sh[512];
    int t = threadIdx.x;
    const int* counts = (const int*)ws + WS_COUNTS;
    float p = (float)counts[t] * (1.0f / (float)NTOT);
    sh[t] = p * logf(p + 1e-10f);
    __syncthreads();
    for (int s = 256; s > 0; s >>= 1) {
        if (t < s) sh[t] += sh[t + s];
        __syncthreads();
    }
    if (t == 0) {
        out[OFF_PERP] = expf(-sh[0]);
        out[OFF_LOSS] = 0.25f * ws[0] / ((float)NTOT * 64.0f);
    }
}

extern "C" void kernel_launch(void* const* d_in, const int* in_sizes, int n_in,
                              void* d_out, int out_size, void* d_ws, size_t ws_size,
                              hipStream_t stream) {
    const float* x  = (const float*)d_in[0];
    const float* cb = (const float*)d_in[1];
    float* out = (float*)d_out;
    float* ws  = (float*)d_ws;

    float* loss_acc = ws;                       // word 0
    int*   counts   = (int*)ws + WS_COUNTS;     // words 1..512
    int*   idx      = (int*)ws + WS_IDX;        // words 2048..
    float* qout     = out + OFF_QUANT;
    float* oh       = out + OFF_OH;

    vq_prep  <<<2,     256, 0, stream>>>(cb, ws);
    vq_argmin<<<NTOT/64, 256, 0, stream>>>(x, cb, ws, idx, counts, loss_acc);
    vq_quant <<<NTOT/256, 256, 0, stream>>>(cb, idx, qout);
    vq_onehot<<<(67108864/4)/256, 256, 0, stream>>>(idx, oh);
    vq_final <<<1,     512, 0, stream>>>(ws, out);
}